// Round 3
// baseline (848.507 us; speedup 1.0000x reference)
//
#include <hip/hip_runtime.h>
#include <hip/hip_bf16.h>
#include <stdint.h>

typedef __attribute__((ext_vector_type(8))) __bf16 bf16x8;
typedef __attribute__((ext_vector_type(4))) float f32x4;

#define MFMA16(a, b, c) __builtin_amdgcn_mfma_f32_16x16x32_bf16(a, b, c, 0, 0, 0)

__device__ __forceinline__ void gload16(const void* g, void* l) {
  __builtin_amdgcn_global_load_lds((const __attribute__((address_space(1))) void*)g,
                                   (__attribute__((address_space(3))) void*)l, 16, 0, 0);
}

// ---------------------------------------------------------------------------
// prep: W1t[j][kk] = (j<512? wq[kk][j]*scale : wkv[kk][j-512]) as bf16  (1536x512)
//       WpT[j][kk] = wproj[kk][j] as bf16                               (512x512)
//       bias1[j]   = j<512? bq[j]*scale : bkv[j-512]                    (1536)
//       bias_frag[h][mi][nj][lane][reg] = bias_table[rel[q][n]][h]      (65536 f32)
// ---------------------------------------------------------------------------
__global__ __launch_bounds__(256) void prep_kernel(
    const float* __restrict__ wq, const float* __restrict__ bq,
    const float* __restrict__ wkv, const float* __restrict__ bkv,
    const float* __restrict__ wproj, const float* __restrict__ btab,
    const int* __restrict__ relidx,
    __bf16* __restrict__ W1t, __bf16* __restrict__ WpT,
    float* __restrict__ bias1, float* __restrict__ bias_frag) {
  const float scale = 0.17677669529663687f;  // 32^-0.5
  int t = blockIdx.x * 256 + threadIdx.x;
  if (t < 786432) {
    int j = t >> 9, kk = t & 511;
    float v = (j < 512) ? wq[kk * 512 + j] * scale : wkv[kk * 1024 + (j - 512)];
    W1t[t] = (__bf16)v;
  } else if (t < 1048576) {
    int u = t - 786432;
    int j = u >> 9, kk = u & 511;
    WpT[u] = (__bf16)wproj[kk * 512 + j];
  } else if (t < 1050112) {
    int j = t - 1048576;
    bias1[j] = (j < 512) ? bq[j] * scale : bkv[j - 512];
  } else if (t < 1115648) {
    int u = t - 1050112;
    int r = u & 3, l = (u >> 2) & 63, nj = (u >> 8) & 3, mi = (u >> 10) & 3, h = u >> 12;
    int qq = mi * 16 + (l >> 4) * 4 + r;
    int nn = nj * 16 + (l & 15);
    bias_frag[u] = btab[relidx[qq * 64 + nn] * 16 + h];
  }
}

// ---------------------------------------------------------------------------
// cvt: q fp32 -> bf16, 8 elems/thread
// ---------------------------------------------------------------------------
__global__ __launch_bounds__(256) void cvt_kernel(const float* __restrict__ in,
                                                  __bf16* __restrict__ out) {
  int t = blockIdx.x * 256 + threadIdx.x;
  const float4* p = (const float4*)in + (size_t)t * 2;
  float4 a = p[0], b = p[1];
  bf16x8 v = {(__bf16)a.x, (__bf16)a.y, (__bf16)a.z, (__bf16)a.w,
              (__bf16)b.x, (__bf16)b.y, (__bf16)b.z, (__bf16)b.w};
  *((bf16x8*)out + t) = v;
}

// ---------------------------------------------------------------------------
// GEMM1: qbf[65536,512] x W1t -> qh [bh][n][d], k [bh][n][d], vT [bh][d][n]
// 128x128 tile, BK=32, 4 waves (2x2), each wave 4x4 fragments of 16x16x32.
// Both operands staged via global_load_lds width-16 (m97 pattern).
// ---------------------------------------------------------------------------
__global__ __launch_bounds__(256) void gemm1_kernel(
    const __bf16* __restrict__ A, const __bf16* __restrict__ W1t,
    const float* __restrict__ bias1,
    __bf16* __restrict__ qh, __bf16* __restrict__ kb, __bf16* __restrict__ vT) {
  __shared__ __bf16 As[128 * 32];  // [row][k]
  __shared__ __bf16 Bs[128 * 32];  // [col n][k]
  int tid = threadIdx.x;
  int w = tid >> 6, l = tid & 63, c = l & 15, g = l >> 4;
  int wm = w >> 1, wn = w & 1;
  int bx = blockIdx.x, by = blockIdx.y;
  int r0 = by * 128, n0 = bx * 128;

  f32x4 acc[4][4] = {};
  int e0 = w * 1024 + l * 8;
  int rn0 = e0 >> 5, rk0 = e0 & 31;
  int e1 = e0 + 512;
  int rn1 = e1 >> 5, rk1 = e1 & 31;

  for (int kt = 0; kt < 16; ++kt) {
    int k0 = kt * 32;
    __syncthreads();
    gload16(A + (size_t)(r0 + rn0) * 512 + k0 + rk0, (void*)(As + w * 1024));
    gload16(A + (size_t)(r0 + rn1) * 512 + k0 + rk1, (void*)(As + w * 1024 + 512));
    gload16(W1t + (size_t)(n0 + rn0) * 512 + k0 + rk0, (void*)(Bs + w * 1024));
    gload16(W1t + (size_t)(n0 + rn1) * 512 + k0 + rk1, (void*)(Bs + w * 1024 + 512));
    __syncthreads();
    bf16x8 af[4], bfr[4];
#pragma unroll
    for (int mi = 0; mi < 4; mi++) af[mi] = *(const bf16x8*)(As + (wm * 64 + mi * 16 + c) * 32 + g * 8);
#pragma unroll
    for (int nj = 0; nj < 4; nj++) bfr[nj] = *(const bf16x8*)(Bs + (wn * 64 + nj * 16 + c) * 32 + g * 8);
#pragma unroll
    for (int mi = 0; mi < 4; mi++)
#pragma unroll
      for (int nj = 0; nj < 4; nj++)
        acc[mi][nj] = MFMA16(af[mi], bfr[nj], acc[mi][nj]);
  }

  float bia[4];
#pragma unroll
  for (int nj = 0; nj < 4; nj++) bia[nj] = bias1[n0 + wn * 64 + nj * 16 + c];
  int rowbase = r0 + wm * 64 + g * 4;
  int colbase = n0 + wn * 64 + c;
#pragma unroll
  for (int mi = 0; mi < 4; mi++) {
#pragma unroll
    for (int nj = 0; nj < 4; nj++) {
      int col = colbase + nj * 16;
      int jj = col & 511;  // region base is 512-aligned
      int h = jj >> 5, d = jj & 31;
#pragma unroll
      for (int r = 0; r < 4; r++) {
        int row = rowbase + mi * 16 + r;
        int b = row >> 6, tok = row & 63;
        float val = acc[mi][nj][r] + bia[nj];
        size_t base = (size_t)(b * 16 + h) * 2048;
        if (bx < 4)
          qh[base + tok * 32 + d] = (__bf16)val;
        else if (bx < 8)
          kb[base + tok * 32 + d] = (__bf16)val;
        else
          vT[base + d * 64 + tok] = (__bf16)val;
      }
    }
  }
}

// ---------------------------------------------------------------------------
// attention: 1 wave per (b,h). S=qh@k^T (bias preloaded into acc), softmax,
// attn out (f32), P->LDS bf16, x=P@vT -> xpart bf16 [b][n][h*32+d]
// ---------------------------------------------------------------------------
__global__ __launch_bounds__(64) void attn_kernel(
    const __bf16* __restrict__ qh, const __bf16* __restrict__ kb,
    const __bf16* __restrict__ vT, const float* __restrict__ bias_frag,
    float* __restrict__ attn_out, __bf16* __restrict__ xpart) {
  __shared__ __bf16 P[64 * 72];
  int bh = blockIdx.x;
  int b = bh >> 4, h = bh & 15;
  int l = threadIdx.x, c = l & 15, g = l >> 4;
  const __bf16* qp = qh + (size_t)bh * 2048;
  const __bf16* kp = kb + (size_t)bh * 2048;
  const __bf16* vp = vT + (size_t)bh * 2048;

  bf16x8 af[4], bfr[4];
#pragma unroll
  for (int mi = 0; mi < 4; mi++) af[mi] = *(const bf16x8*)(qp + (mi * 16 + c) * 32 + g * 8);
#pragma unroll
  for (int nj = 0; nj < 4; nj++) bfr[nj] = *(const bf16x8*)(kp + (nj * 16 + c) * 32 + g * 8);

  f32x4 acc[4][4];
#pragma unroll
  for (int mi = 0; mi < 4; mi++)
#pragma unroll
    for (int nj = 0; nj < 4; nj++)
      acc[mi][nj] = *(const f32x4*)(bias_frag + ((size_t)((h * 4 + mi) * 4 + nj) * 64 + l) * 4);
#pragma unroll
  for (int mi = 0; mi < 4; mi++)
#pragma unroll
    for (int nj = 0; nj < 4; nj++)
      acc[mi][nj] = MFMA16(af[mi], bfr[nj], acc[mi][nj]);

  float* ao = attn_out + (size_t)bh * 4096;
#pragma unroll
  for (int mi = 0; mi < 4; mi++) {
#pragma unroll
    for (int r = 0; r < 4; r++) {
      float m = fmaxf(fmaxf(acc[mi][0][r], acc[mi][1][r]), fmaxf(acc[mi][2][r], acc[mi][3][r]));
      m = fmaxf(m, __shfl_xor(m, 1));
      m = fmaxf(m, __shfl_xor(m, 2));
      m = fmaxf(m, __shfl_xor(m, 4));
      m = fmaxf(m, __shfl_xor(m, 8));
      float p0 = __expf(acc[mi][0][r] - m);
      float p1 = __expf(acc[mi][1][r] - m);
      float p2 = __expf(acc[mi][2][r] - m);
      float p3 = __expf(acc[mi][3][r] - m);
      float s = p0 + p1 + p2 + p3;
      s += __shfl_xor(s, 1);
      s += __shfl_xor(s, 2);
      s += __shfl_xor(s, 4);
      s += __shfl_xor(s, 8);
      float rs = 1.0f / s;
      p0 *= rs; p1 *= rs; p2 *= rs; p3 *= rs;
      int row = mi * 16 + g * 4 + r;
      ao[row * 64 + c] = p0;
      ao[row * 64 + 16 + c] = p1;
      ao[row * 64 + 32 + c] = p2;
      ao[row * 64 + 48 + c] = p3;
      P[row * 72 + c] = (__bf16)p0;
      P[row * 72 + 16 + c] = (__bf16)p1;
      P[row * 72 + 32 + c] = (__bf16)p2;
      P[row * 72 + 48 + c] = (__bf16)p3;
    }
  }
  __syncthreads();

  bf16x8 pa[4][2];
#pragma unroll
  for (int mi = 0; mi < 4; mi++)
#pragma unroll
    for (int kk = 0; kk < 2; kk++)
      pa[mi][kk] = *(const bf16x8*)(P + (mi * 16 + c) * 72 + kk * 32 + g * 8);
  bf16x8 bv[2][2];
#pragma unroll
  for (int dj = 0; dj < 2; dj++)
#pragma unroll
    for (int kk = 0; kk < 2; kk++)
      bv[dj][kk] = *(const bf16x8*)(vp + (c + 16 * dj) * 64 + kk * 32 + g * 8);
  f32x4 xacc[4][2] = {};
#pragma unroll
  for (int mi = 0; mi < 4; mi++)
#pragma unroll
    for (int dj = 0; dj < 2; dj++)
#pragma unroll
      for (int kk = 0; kk < 2; kk++)
        xacc[mi][dj] = MFMA16(pa[mi][kk], bv[dj][kk], xacc[mi][dj]);

  __bf16* xp = xpart + (size_t)b * 64 * 512 + h * 32;
#pragma unroll
  for (int mi = 0; mi < 4; mi++)
#pragma unroll
    for (int dj = 0; dj < 2; dj++)
#pragma unroll
      for (int r = 0; r < 4; r++) {
        int row = mi * 16 + g * 4 + r;
        xp[(size_t)row * 512 + dj * 16 + c] = (__bf16)xacc[mi][dj][r];
      }
}

// ---------------------------------------------------------------------------
// GEMM2: xpart(bf16) x WpT + bproj -> x (f32). Both operands via global_load_lds.
// ---------------------------------------------------------------------------
__global__ __launch_bounds__(256) void gemm2_kernel(
    const __bf16* __restrict__ A, const __bf16* __restrict__ WpT,
    const float* __restrict__ bproj, float* __restrict__ out) {
  __shared__ __bf16 As[128 * 32];
  __shared__ __bf16 Bs[128 * 32];
  int tid = threadIdx.x;
  int w = tid >> 6, l = tid & 63, c = l & 15, g = l >> 4;
  int wm = w >> 1, wn = w & 1;
  int bx = blockIdx.x, by = blockIdx.y;
  int r0 = by * 128, n0 = bx * 128;

  f32x4 acc[4][4] = {};
  int e0 = w * 1024 + l * 8;
  int rn0 = e0 >> 5, rk0 = e0 & 31;
  int e1 = e0 + 512;
  int rn1 = e1 >> 5, rk1 = e1 & 31;

  for (int kt = 0; kt < 16; ++kt) {
    int k0 = kt * 32;
    __syncthreads();
    gload16(A + (size_t)(r0 + rn0) * 512 + k0 + rk0, (void*)(As + w * 1024));
    gload16(A + (size_t)(r0 + rn1) * 512 + k0 + rk1, (void*)(As + w * 1024 + 512));
    gload16(WpT + (size_t)(n0 + rn0) * 512 + k0 + rk0, (void*)(Bs + w * 1024));
    gload16(WpT + (size_t)(n0 + rn1) * 512 + k0 + rk1, (void*)(Bs + w * 1024 + 512));
    __syncthreads();
    bf16x8 af[4], bfr[4];
#pragma unroll
    for (int mi = 0; mi < 4; mi++) af[mi] = *(const bf16x8*)(As + (wm * 64 + mi * 16 + c) * 32 + g * 8);
#pragma unroll
    for (int nj = 0; nj < 4; nj++) bfr[nj] = *(const bf16x8*)(Bs + (wn * 64 + nj * 16 + c) * 32 + g * 8);
#pragma unroll
    for (int mi = 0; mi < 4; mi++)
#pragma unroll
      for (int nj = 0; nj < 4; nj++)
        acc[mi][nj] = MFMA16(af[mi], bfr[nj], acc[mi][nj]);
  }

  float bia[4];
#pragma unroll
  for (int nj = 0; nj < 4; nj++) bia[nj] = bproj[n0 + wn * 64 + nj * 16 + c];
  int rowbase = r0 + wm * 64 + g * 4;
  int colbase = n0 + wn * 64 + c;
#pragma unroll
  for (int mi = 0; mi < 4; mi++)
#pragma unroll
    for (int nj = 0; nj < 4; nj++)
#pragma unroll
      for (int r = 0; r < 4; r++) {
        int row = rowbase + mi * 16 + r;
        out[(size_t)row * 512 + colbase + nj * 16] = acc[mi][nj][r] + bia[nj];
      }
}

// ---------------------------------------------------------------------------
extern "C" void kernel_launch(void* const* d_in, const int* in_sizes, int n_in,
                              void* d_out, int out_size, void* d_ws, size_t ws_size,
                              hipStream_t stream) {
  const float* q = (const float*)d_in[0];
  const float* wq = (const float*)d_in[1];
  const float* bq = (const float*)d_in[2];
  const float* wkv = (const float*)d_in[3];
  const float* bkv = (const float*)d_in[4];
  const float* wproj = (const float*)d_in[5];
  const float* bproj = (const float*)d_in[6];
  const float* btab = (const float*)d_in[7];
  const int* relidx = (const int*)d_in[8];

  float* x_out = (float*)d_out;
  float* attn_out = x_out + 33554432;
  // qbf lives in the attn region of d_out: dead until attn_kernel overwrites it,
  // and gemm1 (its only reader) completes before attn_kernel launches.
  __bf16* qbf = (__bf16*)attn_out;

  char* ws = (char*)d_ws;
  __bf16* qh = (__bf16*)(ws);                  // 67,108,864 B
  __bf16* kb = (__bf16*)(ws + 67108864);       // 67,108,864 B
  __bf16* vT = (__bf16*)(ws + 134217728);      // 67,108,864 B
  __bf16* xpart = (__bf16*)(ws + 201326592);   // 67,108,864 B
  __bf16* W1t = (__bf16*)(ws + 268435456);     //  1,572,864 B
  __bf16* WpT = (__bf16*)(ws + 270008320);     //    524,288 B
  float* bias1 = (float*)(ws + 270532608);     //      6,144 B
  float* bfrag = (float*)(ws + 270538752);     //    262,144 B  (end: 270,800,896)

  hipLaunchKernelGGL(prep_kernel, dim3(4358), dim3(256), 0, stream,
                     wq, bq, wkv, bkv, wproj, btab, relidx, W1t, WpT, bias1, bfrag);
  hipLaunchKernelGGL(cvt_kernel, dim3(16384), dim3(256), 0, stream, q, qbf);
  hipLaunchKernelGGL(gemm1_kernel, dim3(12, 512), dim3(256), 0, stream,
                     qbf, W1t, bias1, qh, kb, vT);
  hipLaunchKernelGGL(attn_kernel, dim3(16384), dim3(64), 0, stream,
                     qh, kb, vT, bfrag, attn_out, xpart);
  hipLaunchKernelGGL(gemm2_kernel, dim3(4, 512), dim3(256), 0, stream,
                     xpart, WpT, bproj, x_out);
}

// Round 5
// 801.505 us; speedup vs baseline: 1.0586x; 1.0586x over previous
//
#include <hip/hip_runtime.h>
#include <hip/hip_bf16.h>
#include <stdint.h>

typedef __attribute__((ext_vector_type(8))) __bf16 bf16x8;
typedef __attribute__((ext_vector_type(4))) float f32x4;

#define MFMA16(a, b, c) __builtin_amdgcn_mfma_f32_16x16x32_bf16(a, b, c, 0, 0, 0)

__device__ __forceinline__ void gload16(const void* g, void* l) {
  __builtin_amdgcn_global_load_lds((const __attribute__((address_space(1))) void*)g,
                                   (__attribute__((address_space(3))) void*)l, 16, 0, 0);
}

// ---------------------------------------------------------------------------
// prep: W1t[j][kk] = (j<512? wq[kk][j]*scale : wkv[kk][j-512]) as bf16  (1536x512)
//       WpT[j][kk] = wproj[kk][j] as bf16                               (512x512)
//       bias1[j]   = j<512? bq[j]*scale : bkv[j-512]                    (1536)
//       bias_frag[h][mi][nj][lane][reg] = bias_table[rel[q][n]][h]      (65536 f32)
// ---------------------------------------------------------------------------
__global__ __launch_bounds__(256) void prep_kernel(
    const float* __restrict__ wq, const float* __restrict__ bq,
    const float* __restrict__ wkv, const float* __restrict__ bkv,
    const float* __restrict__ wproj, const float* __restrict__ btab,
    const int* __restrict__ relidx,
    __bf16* __restrict__ W1t, __bf16* __restrict__ WpT,
    float* __restrict__ bias1, float* __restrict__ bias_frag) {
  const float scale = 0.17677669529663687f;  // 32^-0.5
  int t = blockIdx.x * 256 + threadIdx.x;
  if (t < 786432) {
    int j = t >> 9, kk = t & 511;
    float v = (j < 512) ? wq[kk * 512 + j] * scale : wkv[kk * 1024 + (j - 512)];
    W1t[t] = (__bf16)v;
  } else if (t < 1048576) {
    int u = t - 786432;
    int j = u >> 9, kk = u & 511;
    WpT[u] = (__bf16)wproj[kk * 512 + j];
  } else if (t < 1050112) {
    int j = t - 1048576;
    bias1[j] = (j < 512) ? bq[j] * scale : bkv[j - 512];
  } else if (t < 1115648) {
    int u = t - 1050112;
    int r = u & 3, l = (u >> 2) & 63, nj = (u >> 8) & 3, mi = (u >> 10) & 3, h = u >> 12;
    int qq = mi * 16 + (l >> 4) * 4 + r;
    int nn = nj * 16 + (l & 15);
    bias_frag[u] = btab[relidx[qq * 64 + nn] * 16 + h];
  }
}

// ---------------------------------------------------------------------------
// cvt: q fp32 -> bf16, 8 elems/thread
// ---------------------------------------------------------------------------
__global__ __launch_bounds__(256) void cvt_kernel(const float* __restrict__ in,
                                                  __bf16* __restrict__ out) {
  int t = blockIdx.x * 256 + threadIdx.x;
  const float4* p = (const float4*)in + (size_t)t * 2;
  float4 a = p[0], b = p[1];
  bf16x8 v = {(__bf16)a.x, (__bf16)a.y, (__bf16)a.z, (__bf16)a.w,
              (__bf16)b.x, (__bf16)b.y, (__bf16)b.z, (__bf16)b.w};
  *((bf16x8*)out + t) = v;
}

// ---------------------------------------------------------------------------
// GEMM1: qbf[65536,512] x W1t -> qh, kb, vv   all [bh][n][d] row-major
// 128x128 tile, BK=32, 4 waves (2x2), each wave 4x4 fragments of 16x16x32.
// 1D grid 6144 blocks, XCD-chunked swizzle (T1): each XCD gets a contiguous
// x-fast chunk so the shared 128-row A panel stays in ONE per-XCD L2.
// Unified epilogue: 32B-segment stores for all three regions (no 2B scatter).
// ---------------------------------------------------------------------------
__global__ __launch_bounds__(256) void gemm1_kernel(
    const __bf16* __restrict__ A, const __bf16* __restrict__ W1t,
    const float* __restrict__ bias1,
    __bf16* __restrict__ qh, __bf16* __restrict__ kb, __bf16* __restrict__ vv) {
  __shared__ __bf16 As[128 * 32];  // [row][k]
  __shared__ __bf16 Bs[128 * 32];  // [col n][k]
  int tid = threadIdx.x;
  int w = tid >> 6, l = tid & 63, c = l & 15, g = l >> 4;
  int wm = w >> 1, wn = w & 1;
  // XCD swizzle: nwg=6144, 8 XCDs, 768 blocks/XCD chunk. bijective.
  int bflat = (blockIdx.x & 7) * 768 + (blockIdx.x >> 3);
  int bx = bflat % 12, by = bflat / 12;
  int r0 = by * 128, n0 = bx * 128;

  f32x4 acc[4][4] = {};
  int e0 = w * 1024 + l * 8;
  int rn0 = e0 >> 5, rk0 = e0 & 31;
  int e1 = e0 + 512;
  int rn1 = e1 >> 5, rk1 = e1 & 31;

  for (int kt = 0; kt < 16; ++kt) {
    int k0 = kt * 32;
    __syncthreads();
    gload16(A + (size_t)(r0 + rn0) * 512 + k0 + rk0, (void*)(As + w * 1024));
    gload16(A + (size_t)(r0 + rn1) * 512 + k0 + rk1, (void*)(As + w * 1024 + 512));
    gload16(W1t + (size_t)(n0 + rn0) * 512 + k0 + rk0, (void*)(Bs + w * 1024));
    gload16(W1t + (size_t)(n0 + rn1) * 512 + k0 + rk1, (void*)(Bs + w * 1024 + 512));
    __syncthreads();
    bf16x8 af[4], bfr[4];
#pragma unroll
    for (int mi = 0; mi < 4; mi++) af[mi] = *(const bf16x8*)(As + (wm * 64 + mi * 16 + c) * 32 + g * 8);
#pragma unroll
    for (int nj = 0; nj < 4; nj++) bfr[nj] = *(const bf16x8*)(Bs + (wn * 64 + nj * 16 + c) * 32 + g * 8);
#pragma unroll
    for (int mi = 0; mi < 4; mi++)
#pragma unroll
      for (int nj = 0; nj < 4; nj++)
        acc[mi][nj] = MFMA16(af[mi], bfr[nj], acc[mi][nj]);
  }

  // region select is block-uniform
  __bf16* dst = (bx < 4) ? qh : (bx < 8) ? kb : vv;

  float bia[4];
#pragma unroll
  for (int nj = 0; nj < 4; nj++) bia[nj] = bias1[n0 + wn * 64 + nj * 16 + c];
  int rowbase = r0 + wm * 64 + g * 4;
  int colbase = n0 + wn * 64 + c;
#pragma unroll
  for (int mi = 0; mi < 4; mi++) {
#pragma unroll
    for (int nj = 0; nj < 4; nj++) {
      int col = colbase + nj * 16;
      int jj = col & 511;  // region base is 512-aligned
      int h = jj >> 5, d = jj & 31;
#pragma unroll
      for (int r = 0; r < 4; r++) {
        int row = rowbase + mi * 16 + r;
        int b = row >> 6, tok = row & 63;
        float val = acc[mi][nj][r] + bia[nj];
        dst[(size_t)(b * 16 + h) * 2048 + tok * 32 + d] = (__bf16)val;
      }
    }
  }
}

// ---------------------------------------------------------------------------
// attention: 1 wave per (b,h). S=qh@k^T (bias preloaded into acc), softmax,
// attn out (f32), P->LDS bf16, V staged+transposed via LDS, x=P@V -> xpart.
// ---------------------------------------------------------------------------
__global__ __launch_bounds__(64) void attn_kernel(
    const __bf16* __restrict__ qh, const __bf16* __restrict__ kb,
    const __bf16* __restrict__ vv, const float* __restrict__ bias_frag,
    float* __restrict__ attn_out, __bf16* __restrict__ xpart) {
  __shared__ __bf16 P[64 * 72];
  __shared__ __bf16 Vlds[64 * 34];  // V tile 64 tok x 32 d, row stride 34 (anti-conflict)
  int bh = blockIdx.x;
  int b = bh >> 4, h = bh & 15;
  int l = threadIdx.x, c = l & 15, g = l >> 4;
  const __bf16* qp = qh + (size_t)bh * 2048;
  const __bf16* kp = kb + (size_t)bh * 2048;
  const __bf16* vp = vv + (size_t)bh * 2048;

  // --- issue ALL independent global loads up front (latency hides under QK^T)
  uint4 vst[4];
  const uint4* vg = (const uint4*)vp;  // 4KB tile = 256 x 16B chunks
#pragma unroll
  for (int i = 0; i < 4; i++) vst[i] = vg[l + 64 * i];

  bf16x8 af[4], bfr[4];
#pragma unroll
  for (int mi = 0; mi < 4; mi++) af[mi] = *(const bf16x8*)(qp + (mi * 16 + c) * 32 + g * 8);
#pragma unroll
  for (int nj = 0; nj < 4; nj++) bfr[nj] = *(const bf16x8*)(kp + (nj * 16 + c) * 32 + g * 8);

  f32x4 acc[4][4];
#pragma unroll
  for (int mi = 0; mi < 4; mi++)
#pragma unroll
    for (int nj = 0; nj < 4; nj++)
      acc[mi][nj] = *(const f32x4*)(bias_frag + ((size_t)((h * 4 + mi) * 4 + nj) * 64 + l) * 4);

  // --- stage V into LDS (4B writes keep alignment with stride-34 rows)
#pragma unroll
  for (int i = 0; i < 4; i++) {
    int ch = l + 64 * i;
    int row = ch >> 2, pos = ch & 3;
    uint32_t* pw = (uint32_t*)&Vlds[row * 34 + pos * 8];
    pw[0] = vst[i].x; pw[1] = vst[i].y; pw[2] = vst[i].z; pw[3] = vst[i].w;
  }

  // --- S = qh @ k^T + bias
#pragma unroll
  for (int mi = 0; mi < 4; mi++)
#pragma unroll
    for (int nj = 0; nj < 4; nj++)
      acc[mi][nj] = MFMA16(af[mi], bfr[nj], acc[mi][nj]);

  float* ao = attn_out + (size_t)bh * 4096;
#pragma unroll
  for (int mi = 0; mi < 4; mi++) {
#pragma unroll
    for (int r = 0; r < 4; r++) {
      float m = fmaxf(fmaxf(acc[mi][0][r], acc[mi][1][r]), fmaxf(acc[mi][2][r], acc[mi][3][r]));
      m = fmaxf(m, __shfl_xor(m, 1));
      m = fmaxf(m, __shfl_xor(m, 2));
      m = fmaxf(m, __shfl_xor(m, 4));
      m = fmaxf(m, __shfl_xor(m, 8));
      float p0 = __expf(acc[mi][0][r] - m);
      float p1 = __expf(acc[mi][1][r] - m);
      float p2 = __expf(acc[mi][2][r] - m);
      float p3 = __expf(acc[mi][3][r] - m);
      float s = p0 + p1 + p2 + p3;
      s += __shfl_xor(s, 1);
      s += __shfl_xor(s, 2);
      s += __shfl_xor(s, 4);
      s += __shfl_xor(s, 8);
      float rs = 1.0f / s;
      p0 *= rs; p1 *= rs; p2 *= rs; p3 *= rs;
      int row = mi * 16 + g * 4 + r;
      ao[row * 64 + c] = p0;
      ao[row * 64 + 16 + c] = p1;
      ao[row * 64 + 32 + c] = p2;
      ao[row * 64 + 48 + c] = p3;
      P[row * 72 + c] = (__bf16)p0;
      P[row * 72 + 16 + c] = (__bf16)p1;
      P[row * 72 + 32 + c] = (__bf16)p2;
      P[row * 72 + 48 + c] = (__bf16)p3;
    }
  }
  __syncthreads();

  bf16x8 pa[4][2];
#pragma unroll
  for (int mi = 0; mi < 4; mi++)
#pragma unroll
    for (int kk = 0; kk < 2; kk++)
      pa[mi][kk] = *(const bf16x8*)(P + (mi * 16 + c) * 72 + kk * 32 + g * 8);

  // PV B-frags via transposed LDS reads: bv[dj][kk][e] = V[32kk+8g+e][16dj+c]
  bf16x8 bv[2][2];
#pragma unroll
  for (int dj = 0; dj < 2; dj++)
#pragma unroll
    for (int kk = 0; kk < 2; kk++)
#pragma unroll
      for (int e = 0; e < 8; e++)
        bv[dj][kk][e] = Vlds[(32 * kk + 8 * g + e) * 34 + 16 * dj + c];

  f32x4 xacc[4][2] = {};
#pragma unroll
  for (int mi = 0; mi < 4; mi++)
#pragma unroll
    for (int dj = 0; dj < 2; dj++)
#pragma unroll
      for (int kk = 0; kk < 2; kk++)
        xacc[mi][dj] = MFMA16(pa[mi][kk], bv[dj][kk], xacc[mi][dj]);

  __bf16* xp = xpart + (size_t)b * 64 * 512 + h * 32;
#pragma unroll
  for (int mi = 0; mi < 4; mi++)
#pragma unroll
    for (int dj = 0; dj < 2; dj++)
#pragma unroll
      for (int r = 0; r < 4; r++) {
        int row = mi * 16 + g * 4 + r;
        xp[(size_t)row * 512 + dj * 16 + c] = (__bf16)xacc[mi][dj][r];
      }
}

// ---------------------------------------------------------------------------
// GEMM2: xpart(bf16) x WpT + bproj -> x (f32). Both operands via global_load_lds.
// 1D grid 2048 blocks, XCD-chunked swizzle (T1).
// ---------------------------------------------------------------------------
__global__ __launch_bounds__(256) void gemm2_kernel(
    const __bf16* __restrict__ A, const __bf16* __restrict__ WpT,
    const float* __restrict__ bproj, float* __restrict__ out) {
  __shared__ __bf16 As[128 * 32];
  __shared__ __bf16 Bs[128 * 32];
  int tid = threadIdx.x;
  int w = tid >> 6, l = tid & 63, c = l & 15, g = l >> 4;
  int wm = w >> 1, wn = w & 1;
  // XCD swizzle: nwg=2048, 256 blocks/XCD chunk. bijective.
  int bflat = (blockIdx.x & 7) * 256 + (blockIdx.x >> 3);
  int bx = bflat & 3, by = bflat >> 2;
  int r0 = by * 128, n0 = bx * 128;

  f32x4 acc[4][4] = {};
  int e0 = w * 1024 + l * 8;
  int rn0 = e0 >> 5, rk0 = e0 & 31;
  int e1 = e0 + 512;
  int rn1 = e1 >> 5, rk1 = e1 & 31;

  for (int kt = 0; kt < 16; ++kt) {
    int k0 = kt * 32;
    __syncthreads();
    gload16(A + (size_t)(r0 + rn0) * 512 + k0 + rk0, (void*)(As + w * 1024));
    gload16(A + (size_t)(r0 + rn1) * 512 + k0 + rk1, (void*)(As + w * 1024 + 512));
    gload16(WpT + (size_t)(n0 + rn0) * 512 + k0 + rk0, (void*)(Bs + w * 1024));
    gload16(WpT + (size_t)(n0 + rn1) * 512 + k0 + rk1, (void*)(Bs + w * 1024 + 512));
    __syncthreads();
    bf16x8 af[4], bfr[4];
#pragma unroll
    for (int mi = 0; mi < 4; mi++) af[mi] = *(const bf16x8*)(As + (wm * 64 + mi * 16 + c) * 32 + g * 8);
#pragma unroll
    for (int nj = 0; nj < 4; nj++) bfr[nj] = *(const bf16x8*)(Bs + (wn * 64 + nj * 16 + c) * 32 + g * 8);
#pragma unroll
    for (int mi = 0; mi < 4; mi++)
#pragma unroll
      for (int nj = 0; nj < 4; nj++)
        acc[mi][nj] = MFMA16(af[mi], bfr[nj], acc[mi][nj]);
  }

  float bia[4];
#pragma unroll
  for (int nj = 0; nj < 4; nj++) bia[nj] = bproj[n0 + wn * 64 + nj * 16 + c];
  int rowbase = r0 + wm * 64 + g * 4;
  int colbase = n0 + wn * 64 + c;
#pragma unroll
  for (int mi = 0; mi < 4; mi++)
#pragma unroll
    for (int nj = 0; nj < 4; nj++)
#pragma unroll
      for (int r = 0; r < 4; r++) {
        int row = rowbase + mi * 16 + r;
        out[(size_t)row * 512 + colbase + nj * 16] = acc[mi][nj][r] + bia[nj];
      }
}

// ---------------------------------------------------------------------------
extern "C" void kernel_launch(void* const* d_in, const int* in_sizes, int n_in,
                              void* d_out, int out_size, void* d_ws, size_t ws_size,
                              hipStream_t stream) {
  const float* q = (const float*)d_in[0];
  const float* wq = (const float*)d_in[1];
  const float* bq = (const float*)d_in[2];
  const float* wkv = (const float*)d_in[3];
  const float* bkv = (const float*)d_in[4];
  const float* wproj = (const float*)d_in[5];
  const float* bproj = (const float*)d_in[6];
  const float* btab = (const float*)d_in[7];
  const int* relidx = (const int*)d_in[8];

  float* x_out = (float*)d_out;
  float* attn_out = x_out + 33554432;
  // qbf lives in the attn region of d_out: dead until attn_kernel overwrites it,
  // and gemm1 (its only reader) completes before attn_kernel launches.
  __bf16* qbf = (__bf16*)attn_out;

  char* ws = (char*)d_ws;
  __bf16* qh = (__bf16*)(ws);                  // 67,108,864 B
  __bf16* kb = (__bf16*)(ws + 67108864);       // 67,108,864 B
  __bf16* vv = (__bf16*)(ws + 134217728);      // 67,108,864 B
  __bf16* xpart = (__bf16*)(ws + 201326592);   // 67,108,864 B
  __bf16* W1t = (__bf16*)(ws + 268435456);     //  1,572,864 B
  __bf16* WpT = (__bf16*)(ws + 270008320);     //    524,288 B
  float* bias1 = (float*)(ws + 270532608);     //      6,144 B
  float* bfrag = (float*)(ws + 270538752);     //    262,144 B  (end: 270,800,896)

  hipLaunchKernelGGL(prep_kernel, dim3(4358), dim3(256), 0, stream,
                     wq, bq, wkv, bkv, wproj, btab, relidx, W1t, WpT, bias1, bfrag);
  hipLaunchKernelGGL(cvt_kernel, dim3(16384), dim3(256), 0, stream, q, qbf);
  hipLaunchKernelGGL(gemm1_kernel, dim3(6144), dim3(256), 0, stream,
                     qbf, W1t, bias1, qh, kb, vv);
  hipLaunchKernelGGL(attn_kernel, dim3(16384), dim3(64), 0, stream,
                     qh, kb, vv, bfrag, attn_out, xpart);
  hipLaunchKernelGGL(gemm2_kernel, dim3(2048), dim3(256), 0, stream,
                     xpart, WpT, bproj, x_out);
}